// Round 10
// baseline (751.750 us; speedup 1.0000x reference)
//
#include <hip/hip_runtime.h>

namespace {
constexpr int kB = 256;
constexpr int kS = 2048;
constexpr int kV = 10;
constexpr int kE = 32;
constexpr int kH = 64;
constexpr int kO = 10;
constexpr int kT = 16;      // steps per tile
constexpr int kPad = 68;    // LDS row stride in floats (272 B, 16B-aligned)
// Fold tanh's 2x and log2(e) into weights: s = kC*(xw + h.Wh + b), e^{2p} = 2^s
constexpr float kC = 2.885390081777927f;   // 2*log2(e)

typedef float v4f __attribute__((ext_vector_type(4)));

__device__ __forceinline__ float step_tanh(float s) {
    s = __builtin_amdgcn_fmed3f(s, -26.f, 26.f);
    float e = __builtin_amdgcn_exp2f(s);
    float r = __builtin_amdgcn_rcpf(e + 1.f);
    return fmaf(-2.f, r, 1.f);              // tanh = 1 - 2/(e^{2p}+1)
}

// flat->group addrspacecast on gfx9+ is a low-32-bit truncation (apertures
// are high-bits-only), so the low word of a flat LDS pointer IS the ds offset.
__device__ __forceinline__ uint32_t lds_addr(const void* p) {
    return (uint32_t)(uintptr_t)p;
}

#define FMA4(Q, base)                                   \
    do {                                                \
        a0 = fmaf((Q).x, whc[(base) + 0], a0);          \
        a1 = fmaf((Q).y, whc[(base) + 1], a1);          \
        a2 = fmaf((Q).z, whc[(base) + 2], a2);          \
        a3 = fmaf((Q).w, whc[(base) + 3], a3);          \
    } while (0)

// R6-R8 post-mortem: ds_read writes its destination ASYNCHRONOUSLY within the
// asm block, so without early-clobber ("=&v") the allocator may overlap the
// address input with an output quad -> first returning data corrupts the
// address for later reads. All three failures shared that missing '&'.
// Block is self-contained (waitcnt inside): outputs are retired at block end,
// so no in-flight registers ever cross an asm boundary.
__device__ __forceinline__ void do_steps(float* __restrict__ cur,
                                         const float* __restrict__ prevLast,
                                         const float* __restrict__ xw,
                                         const float* __restrict__ whc, int j)
{
    #pragma unroll
    for (int tl = 0; tl < kT; ++tl) {
        const float* hrow = (tl == 0) ? prevLast : (cur + (tl - 1) * kPad);
        uint32_t ha = lds_addr(hrow);
        v4f q0, q1, q2, q3, q4, q5, q6, q7, q8, q9, qA, qB, qC, qD, qE, qF;
        asm volatile(
            "ds_read_b128 %0, %16 offset:0\n\t"
            "ds_read_b128 %1, %16 offset:16\n\t"
            "ds_read_b128 %2, %16 offset:32\n\t"
            "ds_read_b128 %3, %16 offset:48\n\t"
            "ds_read_b128 %4, %16 offset:64\n\t"
            "ds_read_b128 %5, %16 offset:80\n\t"
            "ds_read_b128 %6, %16 offset:96\n\t"
            "ds_read_b128 %7, %16 offset:112\n\t"
            "ds_read_b128 %8, %16 offset:128\n\t"
            "ds_read_b128 %9, %16 offset:144\n\t"
            "ds_read_b128 %10, %16 offset:160\n\t"
            "ds_read_b128 %11, %16 offset:176\n\t"
            "ds_read_b128 %12, %16 offset:192\n\t"
            "ds_read_b128 %13, %16 offset:208\n\t"
            "ds_read_b128 %14, %16 offset:224\n\t"
            "ds_read_b128 %15, %16 offset:240\n\t"
            "s_waitcnt lgkmcnt(0)"
            : "=&v"(q0), "=&v"(q1), "=&v"(q2), "=&v"(q3),
              "=&v"(q4), "=&v"(q5), "=&v"(q6), "=&v"(q7),
              "=&v"(q8), "=&v"(q9), "=&v"(qA), "=&v"(qB),
              "=&v"(qC), "=&v"(qD), "=&v"(qE), "=&v"(qF)
            : "v"(ha)
            : "memory");
        // all quads retired here — plain C consumption is hazard-free
        float a0 = xw[tl], a1 = 0.f, a2 = 0.f, a3 = 0.f;
        FMA4(q0, 0);  FMA4(q1, 4);  FMA4(q2, 8);  FMA4(q3, 12);
        FMA4(q4, 16); FMA4(q5, 20); FMA4(q6, 24); FMA4(q7, 28);
        FMA4(q8, 32); FMA4(q9, 36); FMA4(qA, 40); FMA4(qB, 44);
        FMA4(qC, 48); FMA4(qD, 52); FMA4(qE, 56); FMA4(qF, 60);
        cur[tl * kPad + j] = step_tanh((a0 + a1) + (a2 + a3));
        // single wave: DS pipe is in-order; the next iteration's volatile
        // asm ("memory" clobber) cannot be crossed by this store, and the
        // reads land after the write in the DS queue -> visible.
    }
}

__device__ __forceinline__ void do_logits(const float* __restrict__ hb,
                                          const float (* __restrict__ WdT)[kPad],
                                          const float* __restrict__ bdL,
                                          float* __restrict__ out, int obase, int j)
{
    #pragma unroll
    for (int r = 0; r < 3; ++r) {
        int f = r * 64 + j;                  // flat (t_local, o), 160 total
        if (f < kT * kO) {
            int tl = f / kO;
            int o  = f - tl * kO;
            const float4* hb4 = reinterpret_cast<const float4*>(hb + tl * kPad);
            const float4* wd4 = reinterpret_cast<const float4*>(&WdT[o][0]);
            float a0 = bdL[o], a1 = 0.f, a2 = 0.f, a3 = 0.f;
            #pragma unroll
            for (int c = 0; c < kH / 4; ++c) {
                float4 h4 = hb4[c];
                float4 w4 = wd4[c];
                a0 = fmaf(h4.x, w4.x, a0);
                a1 = fmaf(h4.y, w4.y, a1);
                a2 = fmaf(h4.z, w4.z, a2);
                a3 = fmaf(h4.w, w4.w, a3);
            }
            out[obase + f] = (a0 + a1) + (a2 + a3);   // coalesced
        }
    }
}

__global__ __launch_bounds__(64, 1)
void rnn_fused(const int* __restrict__ num1, const int* __restrict__ num2,
               const float* __restrict__ embed, const float* __restrict__ Wx,
               const float* __restrict__ Wh, const float* __restrict__ bias,
               const float* __restrict__ Wd, const float* __restrict__ bd,
               float* __restrict__ out)
{
    const int row = blockIdx.x;   // one sequence per block (single wave)
    const int j   = threadIdx.x;  // lane j owns hidden unit j

    __shared__ __align__(16) float TT[kV * kV][kH];     // kC*(xw+b), 100 rows
    __shared__ __align__(16) float hbuf[2][kT][kPad];   // double-buffered h history
    __shared__ __align__(16) float WdT[kO][kPad];
    __shared__ float bdL[kO];

    // ---- one-time per-block setup (single wave: no barriers needed) ----
    {
        float wxc[2 * kE];
        #pragma unroll
        for (int k = 0; k < 2 * kE; ++k) wxc[k] = Wx[k * kH + j];  // Wx column j
        float bj = bias[j];
        float t1[kV], t2[kV];
        #pragma unroll
        for (int v = 0; v < kV; ++v) {
            float a0 = 0.f, a1 = 0.f;
            #pragma unroll
            for (int k = 0; k < kE; ++k) {
                float e = embed[v * kE + k];   // lane-uniform -> s_load
                a0 = fmaf(e, wxc[k], a0);
                a1 = fmaf(e, wxc[kE + k], a1);
            }
            t1[v] = a0; t2[v] = a1;
        }
        #pragma unroll
        for (int v1 = 0; v1 < kV; ++v1)
            #pragma unroll
            for (int v2 = 0; v2 < kV; ++v2)
                TT[v1 * kV + v2][j] = kC * (t1[v1] + t2[v2] + bj);
        #pragma unroll
        for (int o = 0; o < kO; ++o) WdT[o][j] = Wd[j * kO + o];
        if (j < kO) bdL[j] = bd[j];
        hbuf[1][kT - 1][j] = 0.f;   // h_{-1}=0: tile 0 (buf 0) reads buf1 row 15
    }

    float whc[kH];                 // kC * Wh column j
    #pragma unroll
    for (int i = 0; i < kH; ++i) whc[i] = kC * Wh[i * kH + j];

    const int lane16 = j & 15;
    const int nb = row * kS;
    const int orow = row * (kS * kO);

    // tile-0 peel
    int idxv = num1[nb + lane16] * kV + num2[nb + lane16];
    float xw[kT];
    #pragma unroll
    for (int tl = 0; tl < kT; ++tl) {
        int sidx = __builtin_amdgcn_readlane(idxv, tl);   // uniform
        xw[tl] = TT[sidx][j];
    }
    int idx_next = num1[nb + kT + lane16] * kV + num2[nb + kT + lane16];
    do_steps(&hbuf[0][0][0], &hbuf[1][kT - 1][0], xw, whc, j);

    int b = 0;
    for (int t0 = kT; t0 < kS; t0 += kT) {
        idxv = idx_next;
        if (t0 + kT < kS) {
            int tt = nb + t0 + kT + lane16;
            idx_next = num1[tt] * kV + num2[tt];
        }
        #pragma unroll
        for (int tl = 0; tl < kT; ++tl) {
            int sidx = __builtin_amdgcn_readlane(idxv, tl);
            xw[tl] = TT[sidx][j];
        }
        int nbuf = b ^ 1;
        do_steps(&hbuf[nbuf][0][0], &hbuf[b][kT - 1][0], xw, whc, j);
        do_logits(&hbuf[b][0][0], WdT, bdL, out, orow + (t0 - kT) * kO, j);
        b = nbuf;
    }
    do_logits(&hbuf[b][0][0], WdT, bdL, out, orow + (kS - kT) * kO, j);
}
} // namespace

extern "C" void kernel_launch(void* const* d_in, const int* in_sizes, int n_in,
                              void* d_out, int out_size, void* d_ws, size_t ws_size,
                              hipStream_t stream) {
    (void)in_sizes; (void)n_in; (void)d_ws; (void)ws_size; (void)out_size;
    rnn_fused<<<dim3(kB), dim3(64), 0, stream>>>(
        (const int*)d_in[0], (const int*)d_in[1],
        (const float*)d_in[2], (const float*)d_in[3],
        (const float*)d_in[4], (const float*)d_in[5],
        (const float*)d_in[6], (const float*)d_in[7],
        (float*)d_out);
}

// Round 11
// 733.740 us; speedup vs baseline: 1.0245x; 1.0245x over previous
//
#include <hip/hip_runtime.h>

namespace {
constexpr int kB = 256;
constexpr int kS = 2048;
constexpr int kV = 10;
constexpr int kE = 32;
constexpr int kH = 64;
constexpr int kO = 10;
constexpr int kT = 16;      // steps per tile
constexpr int kPad = 68;    // LDS row stride in floats (272 B, 16B-aligned)
// Fold tanh's 2x and log2(e) into weights: s = kC*(xw + h.Wh + b), e^{2p} = 2^s
constexpr float kC = 2.885390081777927f;   // 2*log2(e)

__device__ __forceinline__ float step_tanh(float s) {
    s = __builtin_amdgcn_fmed3f(s, -26.f, 26.f);
    float e = __builtin_amdgcn_exp2f(s);
    float r = __builtin_amdgcn_rcpf(e + 1.f);
    return fmaf(-2.f, r, 1.f);              // tanh = 1 - 2/(e^{2p}+1)
}

#define FMA4(Q, base)                                   \
    do {                                                \
        a0 = fmaf((Q).x, whc[(base) + 0], a0);          \
        a1 = fmaf((Q).y, whc[(base) + 1], a1);          \
        a2 = fmaf((Q).z, whc[(base) + 2], a2);          \
        a3 = fmaf((Q).w, whc[(base) + 3], a3);          \
    } while (0)

// Chain model (fits R1-R9 within ~10%): every DS-dependent hop ~120cy.
// R5's shfl was a SECOND hop (+120); R9's in-asm lgkmcnt(0) serialized the
// whole 16-read stream. This version: ONE hop, full-h, and the read stream
// software-staged (8/4/4) so hardware waits are lgkmcnt(4) and the FMAs
// overlap the remaining stream. Live quads <= 8 -> no allocator batch-split.
__device__ __forceinline__ void do_steps(float* __restrict__ cur,
                                         const float* __restrict__ prevLast,
                                         const float* __restrict__ xw,
                                         const float* __restrict__ whc, int j)
{
    #pragma unroll
    for (int tl = 0; tl < kT; ++tl) {
        const float* hrow = (tl == 0) ? prevLast : (cur + (tl - 1) * kPad);
        const float4* hp = reinterpret_cast<const float4*>(hrow);
        // segment 1: issue 8 broadcast reads
        float4 qa0 = hp[0], qa1 = hp[1], qa2 = hp[2], qa3 = hp[3];
        float4 qb0 = hp[4], qb1 = hp[5], qb2 = hp[6], qb3 = hp[7];
        __builtin_amdgcn_sched_barrier(0);
        // segment 2: consume first 4 (hw wait = lgkmcnt(4)) while 4-7 stream
        float a0 = xw[tl], a1 = 0.f, a2 = 0.f, a3 = 0.f;
        FMA4(qa0, 0);  FMA4(qa1, 4);  FMA4(qa2, 8);  FMA4(qa3, 12);
        __builtin_amdgcn_sched_barrier(0);
        // segment 3: issue next 4 reads under the FMA stream
        float4 qc0 = hp[8], qc1 = hp[9], qc2 = hp[10], qc3 = hp[11];
        __builtin_amdgcn_sched_barrier(0);
        FMA4(qb0, 16); FMA4(qb1, 20); FMA4(qb2, 24); FMA4(qb3, 28);
        __builtin_amdgcn_sched_barrier(0);
        float4 qd0 = hp[12], qd1 = hp[13], qd2 = hp[14], qd3 = hp[15];
        __builtin_amdgcn_sched_barrier(0);
        FMA4(qc0, 32); FMA4(qc1, 36); FMA4(qc2, 40); FMA4(qc3, 44);
        FMA4(qd0, 48); FMA4(qd1, 52); FMA4(qd2, 56); FMA4(qd3, 60);
        cur[tl * kPad + j] = step_tanh((a0 + a1) + (a2 + a3));
        // single wave: DS pipe is in-order; LDS may-alias prevents the
        // compiler from hoisting next step's reads above this store.
    }
}

__device__ __forceinline__ void do_logits(const float* __restrict__ hb,
                                          const float (* __restrict__ WdT)[kPad],
                                          const float* __restrict__ bdL,
                                          float* __restrict__ out, int obase, int j)
{
    #pragma unroll
    for (int r = 0; r < 3; ++r) {
        int f = r * 64 + j;                  // flat (t_local, o), 160 total
        if (f < kT * kO) {
            int tl = f / kO;
            int o  = f - tl * kO;
            const float4* hb4 = reinterpret_cast<const float4*>(hb + tl * kPad);
            const float4* wd4 = reinterpret_cast<const float4*>(&WdT[o][0]);
            float a0 = bdL[o], a1 = 0.f, a2 = 0.f, a3 = 0.f;
            #pragma unroll
            for (int c = 0; c < kH / 4; ++c) {
                float4 h4 = hb4[c];
                float4 w4 = wd4[c];
                a0 = fmaf(h4.x, w4.x, a0);
                a1 = fmaf(h4.y, w4.y, a1);
                a2 = fmaf(h4.z, w4.z, a2);
                a3 = fmaf(h4.w, w4.w, a3);
            }
            out[obase + f] = (a0 + a1) + (a2 + a3);   // coalesced
        }
    }
}

__global__ __launch_bounds__(64, 1)
void rnn_fused(const int* __restrict__ num1, const int* __restrict__ num2,
               const float* __restrict__ embed, const float* __restrict__ Wx,
               const float* __restrict__ Wh, const float* __restrict__ bias,
               const float* __restrict__ Wd, const float* __restrict__ bd,
               float* __restrict__ out)
{
    const int row = blockIdx.x;   // one sequence per block (single wave)
    const int j   = threadIdx.x;  // lane j owns hidden unit j

    __shared__ __align__(16) float TT[kV * kV][kH];     // kC*(xw+b), 100 rows
    __shared__ __align__(16) float hbuf[2][kT][kPad];   // double-buffered h history
    __shared__ __align__(16) float WdT[kO][kPad];
    __shared__ float bdL[kO];

    // ---- one-time per-block setup (single wave: no barriers needed) ----
    {
        float wxc[2 * kE];
        #pragma unroll
        for (int k = 0; k < 2 * kE; ++k) wxc[k] = Wx[k * kH + j];  // Wx column j
        float bj = bias[j];
        float t1[kV], t2[kV];
        #pragma unroll
        for (int v = 0; v < kV; ++v) {
            float a0 = 0.f, a1 = 0.f;
            #pragma unroll
            for (int k = 0; k < kE; ++k) {
                float e = embed[v * kE + k];   // lane-uniform -> s_load
                a0 = fmaf(e, wxc[k], a0);
                a1 = fmaf(e, wxc[kE + k], a1);
            }
            t1[v] = a0; t2[v] = a1;
        }
        #pragma unroll
        for (int v1 = 0; v1 < kV; ++v1)
            #pragma unroll
            for (int v2 = 0; v2 < kV; ++v2)
                TT[v1 * kV + v2][j] = kC * (t1[v1] + t2[v2] + bj);
        #pragma unroll
        for (int o = 0; o < kO; ++o) WdT[o][j] = Wd[j * kO + o];
        if (j < kO) bdL[j] = bd[j];
        hbuf[1][kT - 1][j] = 0.f;   // h_{-1}=0: tile 0 (buf 0) reads buf1 row 15
    }

    float whc[kH];                 // kC * Wh column j
    #pragma unroll
    for (int i = 0; i < kH; ++i) whc[i] = kC * Wh[i * kH + j];

    const int lane16 = j & 15;
    const int nb = row * kS;
    const int orow = row * (kS * kO);

    // tile-0 peel
    int idxv = num1[nb + lane16] * kV + num2[nb + lane16];
    float xw[kT];
    #pragma unroll
    for (int tl = 0; tl < kT; ++tl) {
        int sidx = __builtin_amdgcn_readlane(idxv, tl);   // uniform
        xw[tl] = TT[sidx][j];
    }
    int idx_next = num1[nb + kT + lane16] * kV + num2[nb + kT + lane16];
    do_steps(&hbuf[0][0][0], &hbuf[1][kT - 1][0], xw, whc, j);

    int b = 0;
    for (int t0 = kT; t0 < kS; t0 += kT) {
        idxv = idx_next;
        if (t0 + kT < kS) {
            int tt = nb + t0 + kT + lane16;
            idx_next = num1[tt] * kV + num2[tt];
        }
        #pragma unroll
        for (int tl = 0; tl < kT; ++tl) {
            int sidx = __builtin_amdgcn_readlane(idxv, tl);
            xw[tl] = TT[sidx][j];
        }
        int nbuf = b ^ 1;
        do_steps(&hbuf[nbuf][0][0], &hbuf[b][kT - 1][0], xw, whc, j);
        do_logits(&hbuf[b][0][0], WdT, bdL, out, orow + (t0 - kT) * kO, j);
        b = nbuf;
    }
    do_logits(&hbuf[b][0][0], WdT, bdL, out, orow + (kS - kT) * kO, j);
}
} // namespace

extern "C" void kernel_launch(void* const* d_in, const int* in_sizes, int n_in,
                              void* d_out, int out_size, void* d_ws, size_t ws_size,
                              hipStream_t stream) {
    (void)in_sizes; (void)n_in; (void)d_ws; (void)ws_size; (void)out_size;
    rnn_fused<<<dim3(kB), dim3(64), 0, stream>>>(
        (const int*)d_in[0], (const int*)d_in[1],
        (const float*)d_in[2], (const float*)d_in[3],
        (const float*)d_in[4], (const float*)d_in[5],
        (const float*)d_in[6], (const float*)d_in[7],
        (float*)d_out);
}